// Round 5
// baseline (111.827 us; speedup 1.0000x reference)
//
#include <hip/hip_runtime.h>
#include <math.h>

#define S_TOTAL 4096
#define DDIM    512
#define AXES    72
#define NPROJ   864
#define T_PROP  600
#define SA      (S_TOTAL*AXES)
#define LN_EPS  1e-5f
#define AMP_CUT 4e-6f

typedef __attribute__((ext_vector_type(8))) short short8;
typedef __attribute__((ext_vector_type(4))) float f32x4;

__device__ __forceinline__ float softplus_f(float x) {
    return fmaxf(x, 0.f) + log1pf(expf(-fabsf(x)));
}
__device__ __forceinline__ unsigned short bf_hi(float f) {
    return (unsigned short)(__float_as_uint(f) >> 16);
}

// ---------------- 1. fused LN-stats + bf16 split + W^T split ----------------
__global__ __launch_bounds__(256) void prep_kernel(
        const float* __restrict__ x, const float* __restrict__ gamma,
        const float* __restrict__ beta, const float* __restrict__ W,
        unsigned short* __restrict__ Ahi, unsigned short* __restrict__ Alo,
        unsigned short* __restrict__ WhiT, unsigned short* __restrict__ WloT) {
    __shared__ float Wt[32][33];
    int tid = threadIdx.x;
    int b = blockIdx.x;
    if (b < 1024) {
        int lane = tid & 63, w = tid >> 6;
        int row = b*4 + w;
        const float4* xr = reinterpret_cast<const float4*>(x + (size_t)row * DDIM);
        float4 xv[2] = { xr[lane], xr[lane + 64] };
        float sum = 0.f, ssq = 0.f;
#pragma unroll
        for (int c = 0; c < 2; ++c) {
            sum += (xv[c].x + xv[c].y) + (xv[c].z + xv[c].w);
            ssq += xv[c].x*xv[c].x + xv[c].y*xv[c].y + xv[c].z*xv[c].z + xv[c].w*xv[c].w;
        }
#pragma unroll
        for (int off = 1; off < 64; off <<= 1) {
            sum += __shfl_xor(sum, off);
            ssq += __shfl_xor(ssq, off);
        }
        float m = sum * (1.f/DDIM);
        float r = rsqrtf(ssq * (1.f/DDIM) - m*m + LN_EPS);
        const float4* gp = reinterpret_cast<const float4*>(gamma);
        const float4* bp = reinterpret_cast<const float4*>(beta);
#pragma unroll
        for (int c = 0; c < 2; ++c) {
            float4 gv = gp[lane + 64*c], bv = bp[lane + 64*c];
            float xn[4] = {(xv[c].x-m)*r*gv.x+bv.x, (xv[c].y-m)*r*gv.y+bv.y,
                           (xv[c].z-m)*r*gv.z+bv.z, (xv[c].w-m)*r*gv.w+bv.w};
            ushort4 h4, l4;
            unsigned short* hp = &h4.x;
            unsigned short* lp = &l4.x;
#pragma unroll
            for (int j = 0; j < 4; ++j) {
                unsigned short hi = bf_hi(xn[j]);
                float fhi = __uint_as_float((unsigned)hi << 16);
                hp[j] = hi;
                lp[j] = bf_hi(xn[j] - fhi);
            }
            size_t o = (size_t)row*DDIM + 256*c + lane*4;
            *reinterpret_cast<ushort4*>(&Ahi[o]) = h4;
            *reinterpret_cast<ushort4*>(&Alo[o]) = l4;
        }
    } else {
        int wb = b - 1024;
        int bk = wb / 27, bn = wb - bk*27;
        int tx = tid & 31, ty0 = tid >> 5;
#pragma unroll
        for (int rr = 0; rr < 4; ++rr) {
            int ty = ty0 + rr*8;
            Wt[ty][tx] = W[(size_t)(bk*32 + ty)*NPROJ + bn*32 + tx];
        }
        __syncthreads();
#pragma unroll
        for (int rr = 0; rr < 4; ++rr) {
            int ny = ty0 + rr*8;
            int n = bn*32 + ny;
            int k = bk*32 + tx;
            float f = Wt[tx][ny];
            unsigned short hi = bf_hi(f);
            float fhi = __uint_as_float((unsigned)hi << 16);
            WhiT[(size_t)n*DDIM + k] = hi;
            WloT[(size_t)n*DDIM + k] = bf_hi(f - fhi);
        }
    }
}

// ---------------- 2. split-bf16 MFMA GEMM, fused-segment staging ----------------
// Stage {Ahi,Alo,WhiT,WloT} for one 64-wide k-chunk together; fire 3 MFMA
// segments (hi*hi, lo*hi, hi*lo) from it. Reg double-buffer: issue next
// chunk's loads before compute, commit to LDS after the barrier.
__global__ __launch_bounds__(256) void gemm_kernel(
        const unsigned short* __restrict__ Ahi, const unsigned short* __restrict__ Alo,
        const unsigned short* __restrict__ WhiT, const unsigned short* __restrict__ WloT,
        const float* __restrict__ bias,
        float* __restrict__ P, float* __restrict__ out) {
    __shared__ __align__(16) unsigned short Xs[2][64][72];   // [hi/lo][s][k+pad8]
    __shared__ __align__(16) unsigned short Ws2[2][96][72];  // [hi/lo][n][k+pad8]

    int tid  = threadIdx.x;
    int lane = tid & 63;
    int wv   = tid >> 6;
    int wm   = wv & 1;
    int wn   = wv >> 1;
    int sBase = blockIdx.x * 64;
    int nBase = blockIdx.y * 96;

    f32x4 acc[2][3] = {};
    uint4 pf[10];

    int rX[2], cX[2], rW[3], cW[3];
#pragma unroll
    for (int j = 0; j < 2; ++j) { int ch = j*256 + tid; rX[j] = ch >> 3; cX[j] = ch & 7; }
#pragma unroll
    for (int j = 0; j < 3; ++j) { int ch = j*256 + tid; rW[j] = ch >> 3; cW[j] = ch & 7; }

    const unsigned short* ap[2] = {Ahi, Alo};
    const unsigned short* wp[2] = {WhiT, WloT};

    // issue chunk-0 loads
#pragma unroll
    for (int p = 0; p < 2; ++p) {
#pragma unroll
        for (int j = 0; j < 2; ++j)
            pf[p*2+j] = *reinterpret_cast<const uint4*>(ap[p] + (size_t)(sBase+rX[j])*DDIM + cX[j]*8);
#pragma unroll
        for (int j = 0; j < 3; ++j)
            pf[4+p*3+j] = *reinterpret_cast<const uint4*>(wp[p] + (size_t)(nBase+rW[j])*DDIM + cW[j]*8);
    }

#pragma unroll 1
    for (int kt = 0; kt < 8; ++kt) {
        // commit chunk kt (regs -> LDS); previous compute finished at loop-end barrier
#pragma unroll
        for (int p = 0; p < 2; ++p) {
#pragma unroll
            for (int j = 0; j < 2; ++j)
                *reinterpret_cast<uint4*>(&Xs[p][rX[j]][cX[j]*8]) = pf[p*2+j];
#pragma unroll
            for (int j = 0; j < 3; ++j)
                *reinterpret_cast<uint4*>(&Ws2[p][rW[j]][cW[j]*8]) = pf[4+p*3+j];
        }
        __syncthreads();
        // issue chunk kt+1 (latency hidden under this chunk's compute)
        if (kt < 7) {
            int k0 = (kt+1)*64;
#pragma unroll
            for (int p = 0; p < 2; ++p) {
#pragma unroll
                for (int j = 0; j < 2; ++j)
                    pf[p*2+j] = *reinterpret_cast<const uint4*>(ap[p] + (size_t)(sBase+rX[j])*DDIM + k0 + cX[j]*8);
#pragma unroll
                for (int j = 0; j < 3; ++j)
                    pf[4+p*3+j] = *reinterpret_cast<const uint4*>(wp[p] + (size_t)(nBase+rW[j])*DDIM + k0 + cW[j]*8);
            }
        }
        // compute: 2 kk-halves x (10 ds_read_b128 + 18 MFMA)
#pragma unroll
        for (int kk = 0; kk < 2; ++kk) {
            int koff = kk*32 + ((lane>>4)<<3);
            short8 xh[2], xl[2], wh[3], wl[3];
#pragma unroll
            for (int mi = 0; mi < 2; ++mi) {
                xh[mi] = *reinterpret_cast<const short8*>(&Xs[0][wm*32 + mi*16 + (lane&15)][koff]);
                xl[mi] = *reinterpret_cast<const short8*>(&Xs[1][wm*32 + mi*16 + (lane&15)][koff]);
            }
#pragma unroll
            for (int nf = 0; nf < 3; ++nf) {
                wh[nf] = *reinterpret_cast<const short8*>(&Ws2[0][wn*48 + nf*16 + (lane&15)][koff]);
                wl[nf] = *reinterpret_cast<const short8*>(&Ws2[1][wn*48 + nf*16 + (lane&15)][koff]);
            }
#pragma unroll
            for (int mi = 0; mi < 2; ++mi)
#pragma unroll
                for (int nf = 0; nf < 3; ++nf)
                    acc[mi][nf] = __builtin_amdgcn_mfma_f32_16x16x32_bf16(wh[nf], xh[mi], acc[mi][nf], 0, 0, 0);
#pragma unroll
            for (int mi = 0; mi < 2; ++mi)
#pragma unroll
                for (int nf = 0; nf < 3; ++nf)
                    acc[mi][nf] = __builtin_amdgcn_mfma_f32_16x16x32_bf16(wh[nf], xl[mi], acc[mi][nf], 0, 0, 0);
#pragma unroll
            for (int mi = 0; mi < 2; ++mi)
#pragma unroll
                for (int nf = 0; nf < 3; ++nf)
                    acc[mi][nf] = __builtin_amdgcn_mfma_f32_16x16x32_bf16(wl[nf], xh[mi], acc[mi][nf], 0, 0, 0);
        }
        __syncthreads();
    }

    // epilogue: D rows = n, D cols = s (coalesced); transcendentals only where needed
    int sCol = sBase + wm*32 + (lane & 15);
    int nRowBase = nBase + wn*48 + ((lane>>4)<<2);
#pragma unroll
    for (int mi = 0; mi < 2; ++mi) {
        int s = sCol + mi*16;
#pragma unroll
        for (int nf = 0; nf < 3; ++nf) {
#pragma unroll
            for (int r = 0; r < 4; ++r) {
                int n = nRowBase + nf*16 + r;
                float val = acc[mi][nf][r] + bias[n];
                int ip = (n * 3641) >> 18;   // n / 72
                int a  = n - ip * 72;
                float res;
                if (ip == 0 || ip == 2)      res = sqrtf(softplus_f(val));
                else if (ip == 1 || ip == 3 || ip == 9 || ip == 11) res = softplus_f(val);
                else                          res = val;
                float* dst = (ip < 8) ? (P + (size_t)ip * SA)
                                      : (out + (size_t)(ip - 7) * SA);
                dst[(size_t)a * S_TOTAL + s] = res;
            }
        }
    }
}

// ---------------- 3. oscillator: order-2 recurrences + rotation scatter ----------------
template<int STEPS>
__device__ __forceinline__ void osc_chunk(
        float& v1a, float& v1b, float& v2a, float& v2b,
        float p1, float q1, float p2, float q2,
        float& acc0, float& acc1, int lane, int lane4) {
#pragma unroll
    for (int i = 0; i < STEPS/2; ++i) {
        {
            const int dt = 2*i;
            v1b = fmaf(p1, v1a, -(q1*v1b));
            v2b = fmaf(p2, v2a, -(q2*v2b));
            float v = v1b + v2b;
            if (dt == 0) {
                acc0 += v;
            } else {
                int addr = (lane4 + (((64-dt)&63)<<2)) & 255;
                float vr = __int_as_float(__builtin_amdgcn_ds_bpermute(addr, __float_as_int(v)));
                bool nw = lane >= dt;
                acc0 += nw ? vr : 0.f;
                acc1 += nw ? 0.f : vr;
            }
        }
        {
            const int dt = 2*i + 1;
            v1a = fmaf(p1, v1b, -(q1*v1a));
            v2a = fmaf(p2, v2b, -(q2*v2a));
            float v = v1a + v2a;
            int addr = (lane4 + (((64-dt)&63)<<2)) & 255;
            float vr = __int_as_float(__builtin_amdgcn_ds_bpermute(addr, __float_as_int(v)));
            bool nw = lane >= dt;
            acc0 += nw ? vr : 0.f;
            acc1 += nw ? 0.f : vr;
        }
    }
}

__global__ __launch_bounds__(256) void osc_kernel(const float* __restrict__ P,
                                                  float* __restrict__ kin) {
    int tid  = threadIdx.x;
    int lane = tid & 63;
    int wv   = tid >> 6;
    int lane4 = lane << 2;
    int sBase = blockIdx.x * 64;
    int a  = blockIdx.y * 2 + (wv >> 1);
    int t0 = (wv & 1) * 300;
    float t0f = (float)t0;

    size_t base = (size_t)a * S_TOTAL + sBase + lane;
    float om1 = P[0*(size_t)SA + base], d1 = P[1*(size_t)SA + base];
    float om2 = P[2*(size_t)SA + base], d2 = P[3*(size_t)SA + base];
    float c1  = P[4*(size_t)SA + base], c2  = P[5*(size_t)SA + base];
    float ph1 = P[6*(size_t)SA + base], ph2 = P[7*(size_t)SA + base];

    float dcf1 = __expf(-0.5f*d1);
    float e1   = c1 * __expf(-0.5f*d1*t0f);
    float s0, c0, so, co;
    __sincosf(fmaf(t0f, om1, ph1), &s0, &c0);
    __sincosf(om1, &so, &co);
    float inv1 = __expf(0.5f*d1);
    float p1 = 2.f*dcf1*co, q1 = dcf1*dcf1;
    float v1a = e1*inv1*(s0*co - c0*so);
    float cs2 = fmaf(2.f*co, co, -1.f), sn2 = 2.f*so*co;
    float v1b = e1*inv1*inv1*(s0*cs2 - c0*sn2);
    float amp1 = fabsf(e1);
    float dq1 = q1*q1; dq1*=dq1; dq1*=dq1; dq1*=dq1; dq1*=dq1;
    float dcf2 = __expf(-0.5f*d2);
    float e2   = c2 * __expf(-0.5f*d2*t0f);
    __sincosf(fmaf(t0f, om2, ph2), &s0, &c0);
    __sincosf(om2, &so, &co);
    float inv2 = __expf(0.5f*d2);
    float p2 = 2.f*dcf2*co, q2 = dcf2*dcf2;
    float v2a = e2*inv2*(s0*co - c0*so);
    cs2 = fmaf(2.f*co, co, -1.f); sn2 = 2.f*so*co;
    float v2b = e2*inv2*inv2*(s0*cs2 - c0*sn2);
    float amp2 = fabsf(e2);
    float dq2 = q2*q2; dq2*=dq2; dq2*=dq2; dq2*=dq2; dq2*=dq2;

    float acc0 = 0.f, acc1 = 0.f;
    float* kinA = kin + (size_t)a * S_TOTAL;
    int jBase = sBase + t0;
    int ran = 0;

#pragma unroll 1
    for (int c = 0; c < 5; ++c) {
        if (__all(fmaxf(amp1, amp2) < AMP_CUT)) break;
        if (c < 4) osc_chunk<64>(v1a, v1b, v2a, v2b, p1, q1, p2, q2, acc0, acc1, lane, lane4);
        else       osc_chunk<44>(v1a, v1b, v2a, v2b, p1, q1, p2, q2, acc0, acc1, lane, lane4);
        int j = jBase + lane;
        if (j < S_TOTAL) unsafeAtomicAdd(&kinA[j], acc0);
        acc0 = acc1; acc1 = 0.f;
        jBase += 64;
        amp1 *= dq1; amp2 *= dq2;
        ran = 1;
        if (jBase >= S_TOTAL) { ran = 0; break; }
    }
    if (ran) {
        int j = jBase + lane;
        if (j < S_TOTAL) unsafeAtomicAdd(&kinA[j], acc0);
    }
}

// ---------------- launch ----------------
extern "C" void kernel_launch(void* const* d_in, const int* in_sizes, int n_in,
                              void* d_out, int out_size, void* d_ws, size_t ws_size,
                              hipStream_t stream) {
    const float* x     = (const float*)d_in[0];
    const float* gamma = (const float*)d_in[1];
    const float* beta  = (const float*)d_in[2];
    const float* W     = (const float*)d_in[3];
    const float* b     = (const float*)d_in[4];
    float* out = (float*)d_out;

    unsigned char* wsb = (unsigned char*)d_ws;
    float* P    = (float*)wsb;                               // 8*SA f32
    unsigned short* Ahi  = (unsigned short*)(wsb + 9437184);
    unsigned short* Alo  = Ahi  + (size_t)S_TOTAL*DDIM;
    unsigned short* WhiT = Alo  + (size_t)S_TOTAL*DDIM;
    unsigned short* WloT = WhiT + (size_t)NPROJ*DDIM;

    hipMemsetAsync(d_out, 0, (size_t)SA * sizeof(float), stream);

    prep_kernel<<<dim3(1024 + 432), dim3(256), 0, stream>>>(x, gamma, beta, W,
                                                            Ahi, Alo, WhiT, WloT);
    gemm_kernel<<<dim3(S_TOTAL/64, NPROJ/96), dim3(256), 0, stream>>>(Ahi, Alo, WhiT, WloT,
                                                                      b, P, out);
    osc_kernel<<<dim3(S_TOTAL/64, AXES/2), dim3(256), 0, stream>>>(P, out);
}

// Round 6
// 111.025 us; speedup vs baseline: 1.0072x; 1.0072x over previous
//
#include <hip/hip_runtime.h>
#include <math.h>

#define S_TOTAL 4096
#define DDIM    512
#define AXES    72
#define NPROJ   864
#define T_PROP  600
#define SA      (S_TOTAL*AXES)
#define LN_EPS  1e-5f
#define AMP_CUT 4e-6f

typedef __attribute__((ext_vector_type(8))) short short8;
typedef __attribute__((ext_vector_type(4))) float f32x4;

__device__ __forceinline__ float softplus_f(float x) {
    return fmaxf(x, 0.f) + log1pf(expf(-fabsf(x)));
}
__device__ __forceinline__ unsigned short bf_hi(float f) {
    return (unsigned short)(__float_as_uint(f) >> 16);
}

// ---------------- 1. fused LN-stats + bf16 split + W^T split ----------------
__global__ __launch_bounds__(256) void prep_kernel(
        const float* __restrict__ x, const float* __restrict__ gamma,
        const float* __restrict__ beta, const float* __restrict__ W,
        unsigned short* __restrict__ Ahi, unsigned short* __restrict__ Alo,
        unsigned short* __restrict__ WhiT, unsigned short* __restrict__ WloT) {
    __shared__ float Wt[32][33];
    int tid = threadIdx.x;
    int b = blockIdx.x;
    if (b < 1024) {
        int lane = tid & 63, w = tid >> 6;
        int row = b*4 + w;
        const float4* xr = reinterpret_cast<const float4*>(x + (size_t)row * DDIM);
        float4 xv[2] = { xr[lane], xr[lane + 64] };
        float sum = 0.f, ssq = 0.f;
#pragma unroll
        for (int c = 0; c < 2; ++c) {
            sum += (xv[c].x + xv[c].y) + (xv[c].z + xv[c].w);
            ssq += xv[c].x*xv[c].x + xv[c].y*xv[c].y + xv[c].z*xv[c].z + xv[c].w*xv[c].w;
        }
#pragma unroll
        for (int off = 1; off < 64; off <<= 1) {
            sum += __shfl_xor(sum, off);
            ssq += __shfl_xor(ssq, off);
        }
        float m = sum * (1.f/DDIM);
        float r = rsqrtf(ssq * (1.f/DDIM) - m*m + LN_EPS);
        const float4* gp = reinterpret_cast<const float4*>(gamma);
        const float4* bp = reinterpret_cast<const float4*>(beta);
#pragma unroll
        for (int c = 0; c < 2; ++c) {
            float4 gv = gp[lane + 64*c], bv = bp[lane + 64*c];
            float xn[4] = {(xv[c].x-m)*r*gv.x+bv.x, (xv[c].y-m)*r*gv.y+bv.y,
                           (xv[c].z-m)*r*gv.z+bv.z, (xv[c].w-m)*r*gv.w+bv.w};
            ushort4 h4, l4;
            unsigned short* hp = &h4.x;
            unsigned short* lp = &l4.x;
#pragma unroll
            for (int j = 0; j < 4; ++j) {
                unsigned short hi = bf_hi(xn[j]);
                float fhi = __uint_as_float((unsigned)hi << 16);
                hp[j] = hi;
                lp[j] = bf_hi(xn[j] - fhi);
            }
            size_t o = (size_t)row*DDIM + 256*c + lane*4;
            *reinterpret_cast<ushort4*>(&Ahi[o]) = h4;
            *reinterpret_cast<ushort4*>(&Alo[o]) = l4;
        }
    } else {
        int wb = b - 1024;
        int bk = wb / 27, bn = wb - bk*27;
        int tx = tid & 31, ty0 = tid >> 5;
#pragma unroll
        for (int rr = 0; rr < 4; ++rr) {
            int ty = ty0 + rr*8;
            Wt[ty][tx] = W[(size_t)(bk*32 + ty)*NPROJ + bn*32 + tx];
        }
        __syncthreads();
#pragma unroll
        for (int rr = 0; rr < 4; ++rr) {
            int ny = ty0 + rr*8;
            int n = bn*32 + ny;
            int k = bk*32 + tx;
            float f = Wt[tx][ny];
            unsigned short hi = bf_hi(f);
            float fhi = __uint_as_float((unsigned)hi << 16);
            WhiT[(size_t)n*DDIM + k] = hi;
            WloT[(size_t)n*DDIM + k] = bf_hi(f - fhi);
        }
    }
}

// ---------------- 2. split-bf16 MFMA GEMM, fused-segment staging ----------------
// __launch_bounds__(256, 2): VGPR cap 256 so the pf[10] reg double-buffer
// stays in registers (R4's plain (256) capped at 68 VGPR -> 112 MB spill).
__global__ __launch_bounds__(256, 2) void gemm_kernel(
        const unsigned short* __restrict__ Ahi, const unsigned short* __restrict__ Alo,
        const unsigned short* __restrict__ WhiT, const unsigned short* __restrict__ WloT,
        const float* __restrict__ bias,
        float* __restrict__ P, float* __restrict__ out) {
    __shared__ __align__(16) unsigned short Xs[2][64][72];   // [hi/lo][s][k+pad8]
    __shared__ __align__(16) unsigned short Ws2[2][96][72];  // [hi/lo][n][k+pad8]

    int tid  = threadIdx.x;
    int lane = tid & 63;
    int wv   = tid >> 6;
    int wm   = wv & 1;
    int wn   = wv >> 1;
    int sBase = blockIdx.x * 64;
    int nBase = blockIdx.y * 96;

    f32x4 acc[2][3] = {};
    uint4 pf[10];

    int rX[2], cX[2], rW[3], cW[3];
#pragma unroll
    for (int j = 0; j < 2; ++j) { int ch = j*256 + tid; rX[j] = ch >> 3; cX[j] = ch & 7; }
#pragma unroll
    for (int j = 0; j < 3; ++j) { int ch = j*256 + tid; rW[j] = ch >> 3; cW[j] = ch & 7; }

    const unsigned short* ap[2] = {Ahi, Alo};
    const unsigned short* wp[2] = {WhiT, WloT};

    // issue chunk-0 loads
#pragma unroll
    for (int p = 0; p < 2; ++p) {
#pragma unroll
        for (int j = 0; j < 2; ++j)
            pf[p*2+j] = *reinterpret_cast<const uint4*>(ap[p] + (size_t)(sBase+rX[j])*DDIM + cX[j]*8);
#pragma unroll
        for (int j = 0; j < 3; ++j)
            pf[4+p*3+j] = *reinterpret_cast<const uint4*>(wp[p] + (size_t)(nBase+rW[j])*DDIM + cW[j]*8);
    }

#pragma unroll 1
    for (int kt = 0; kt < 8; ++kt) {
        // commit chunk kt (regs -> LDS)
#pragma unroll
        for (int p = 0; p < 2; ++p) {
#pragma unroll
            for (int j = 0; j < 2; ++j)
                *reinterpret_cast<uint4*>(&Xs[p][rX[j]][cX[j]*8]) = pf[p*2+j];
#pragma unroll
            for (int j = 0; j < 3; ++j)
                *reinterpret_cast<uint4*>(&Ws2[p][rW[j]][cW[j]*8]) = pf[4+p*3+j];
        }
        __syncthreads();
        // issue chunk kt+1 (latency hidden under this chunk's compute)
        if (kt < 7) {
            int k0 = (kt+1)*64;
#pragma unroll
            for (int p = 0; p < 2; ++p) {
#pragma unroll
                for (int j = 0; j < 2; ++j)
                    pf[p*2+j] = *reinterpret_cast<const uint4*>(ap[p] + (size_t)(sBase+rX[j])*DDIM + k0 + cX[j]*8);
#pragma unroll
                for (int j = 0; j < 3; ++j)
                    pf[4+p*3+j] = *reinterpret_cast<const uint4*>(wp[p] + (size_t)(nBase+rW[j])*DDIM + k0 + cW[j]*8);
            }
        }
        // compute: 2 kk-halves x (10 ds_read_b128 + 18 MFMA)
#pragma unroll
        for (int kk = 0; kk < 2; ++kk) {
            int koff = kk*32 + ((lane>>4)<<3);
            short8 xh[2], xl[2], wh[3], wl[3];
#pragma unroll
            for (int mi = 0; mi < 2; ++mi) {
                xh[mi] = *reinterpret_cast<const short8*>(&Xs[0][wm*32 + mi*16 + (lane&15)][koff]);
                xl[mi] = *reinterpret_cast<const short8*>(&Xs[1][wm*32 + mi*16 + (lane&15)][koff]);
            }
#pragma unroll
            for (int nf = 0; nf < 3; ++nf) {
                wh[nf] = *reinterpret_cast<const short8*>(&Ws2[0][wn*48 + nf*16 + (lane&15)][koff]);
                wl[nf] = *reinterpret_cast<const short8*>(&Ws2[1][wn*48 + nf*16 + (lane&15)][koff]);
            }
#pragma unroll
            for (int mi = 0; mi < 2; ++mi)
#pragma unroll
                for (int nf = 0; nf < 3; ++nf)
                    acc[mi][nf] = __builtin_amdgcn_mfma_f32_16x16x32_bf16(wh[nf], xh[mi], acc[mi][nf], 0, 0, 0);
#pragma unroll
            for (int mi = 0; mi < 2; ++mi)
#pragma unroll
                for (int nf = 0; nf < 3; ++nf)
                    acc[mi][nf] = __builtin_amdgcn_mfma_f32_16x16x32_bf16(wh[nf], xl[mi], acc[mi][nf], 0, 0, 0);
#pragma unroll
            for (int mi = 0; mi < 2; ++mi)
#pragma unroll
                for (int nf = 0; nf < 3; ++nf)
                    acc[mi][nf] = __builtin_amdgcn_mfma_f32_16x16x32_bf16(wl[nf], xh[mi], acc[mi][nf], 0, 0, 0);
        }
        __syncthreads();
    }

    // epilogue: D rows = n, D cols = s (coalesced); transcendentals only where needed
    int sCol = sBase + wm*32 + (lane & 15);
    int nRowBase = nBase + wn*48 + ((lane>>4)<<2);
#pragma unroll
    for (int mi = 0; mi < 2; ++mi) {
        int s = sCol + mi*16;
#pragma unroll
        for (int nf = 0; nf < 3; ++nf) {
#pragma unroll
            for (int r = 0; r < 4; ++r) {
                int n = nRowBase + nf*16 + r;
                float val = acc[mi][nf][r] + bias[n];
                int ip = (n * 3641) >> 18;   // n / 72
                int a  = n - ip * 72;
                float res;
                if (ip == 0 || ip == 2)      res = sqrtf(softplus_f(val));
                else if (ip == 1 || ip == 3 || ip == 9 || ip == 11) res = softplus_f(val);
                else                          res = val;
                float* dst = (ip < 8) ? (P + (size_t)ip * SA)
                                      : (out + (size_t)(ip - 7) * SA);
                dst[(size_t)a * S_TOTAL + s] = res;
            }
        }
    }
}

// ---------------- 3. oscillator: order-2 recurrences + rotation scatter ----------------
template<int STEPS>
__device__ __forceinline__ void osc_chunk(
        float& v1a, float& v1b, float& v2a, float& v2b,
        float p1, float q1, float p2, float q2,
        float& acc0, float& acc1, int lane, int lane4) {
#pragma unroll
    for (int i = 0; i < STEPS/2; ++i) {
        {
            const int dt = 2*i;
            v1b = fmaf(p1, v1a, -(q1*v1b));
            v2b = fmaf(p2, v2a, -(q2*v2b));
            float v = v1b + v2b;
            if (dt == 0) {
                acc0 += v;
            } else {
                int addr = (lane4 + (((64-dt)&63)<<2)) & 255;
                float vr = __int_as_float(__builtin_amdgcn_ds_bpermute(addr, __float_as_int(v)));
                bool nw = lane >= dt;
                acc0 += nw ? vr : 0.f;
                acc1 += nw ? 0.f : vr;
            }
        }
        {
            const int dt = 2*i + 1;
            v1a = fmaf(p1, v1b, -(q1*v1a));
            v2a = fmaf(p2, v2b, -(q2*v2a));
            float v = v1a + v2a;
            int addr = (lane4 + (((64-dt)&63)<<2)) & 255;
            float vr = __int_as_float(__builtin_amdgcn_ds_bpermute(addr, __float_as_int(v)));
            bool nw = lane >= dt;
            acc0 += nw ? vr : 0.f;
            acc1 += nw ? 0.f : vr;
        }
    }
}

__global__ __launch_bounds__(256) void osc_kernel(const float* __restrict__ P,
                                                  float* __restrict__ kin) {
    int tid  = threadIdx.x;
    int lane = tid & 63;
    int wv   = tid >> 6;
    int lane4 = lane << 2;
    int sBase = blockIdx.x * 64;
    int a  = blockIdx.y * 2 + (wv >> 1);
    int t0 = (wv & 1) * 300;
    float t0f = (float)t0;

    size_t base = (size_t)a * S_TOTAL + sBase + lane;
    float om1 = P[0*(size_t)SA + base], d1 = P[1*(size_t)SA + base];
    float om2 = P[2*(size_t)SA + base], d2 = P[3*(size_t)SA + base];
    float c1  = P[4*(size_t)SA + base], c2  = P[5*(size_t)SA + base];
    float ph1 = P[6*(size_t)SA + base], ph2 = P[7*(size_t)SA + base];

    float dcf1 = __expf(-0.5f*d1);
    float e1   = c1 * __expf(-0.5f*d1*t0f);
    float s0, c0, so, co;
    __sincosf(fmaf(t0f, om1, ph1), &s0, &c0);
    __sincosf(om1, &so, &co);
    float inv1 = __expf(0.5f*d1);
    float p1 = 2.f*dcf1*co, q1 = dcf1*dcf1;
    float v1a = e1*inv1*(s0*co - c0*so);
    float cs2 = fmaf(2.f*co, co, -1.f), sn2 = 2.f*so*co;
    float v1b = e1*inv1*inv1*(s0*cs2 - c0*sn2);
    float amp1 = fabsf(e1);
    float dq1 = q1*q1; dq1*=dq1; dq1*=dq1; dq1*=dq1; dq1*=dq1;
    float dcf2 = __expf(-0.5f*d2);
    float e2   = c2 * __expf(-0.5f*d2*t0f);
    __sincosf(fmaf(t0f, om2, ph2), &s0, &c0);
    __sincosf(om2, &so, &co);
    float inv2 = __expf(0.5f*d2);
    float p2 = 2.f*dcf2*co, q2 = dcf2*dcf2;
    float v2a = e2*inv2*(s0*co - c0*so);
    cs2 = fmaf(2.f*co, co, -1.f); sn2 = 2.f*so*co;
    float v2b = e2*inv2*inv2*(s0*cs2 - c0*sn2);
    float amp2 = fabsf(e2);
    float dq2 = q2*q2; dq2*=dq2; dq2*=dq2; dq2*=dq2; dq2*=dq2;

    float acc0 = 0.f, acc1 = 0.f;
    float* kinA = kin + (size_t)a * S_TOTAL;
    int jBase = sBase + t0;
    int ran = 0;

#pragma unroll 1
    for (int c = 0; c < 5; ++c) {
        if (__all(fmaxf(amp1, amp2) < AMP_CUT)) break;
        if (c < 4) osc_chunk<64>(v1a, v1b, v2a, v2b, p1, q1, p2, q2, acc0, acc1, lane, lane4);
        else       osc_chunk<44>(v1a, v1b, v2a, v2b, p1, q1, p2, q2, acc0, acc1, lane, lane4);
        int j = jBase + lane;
        if (j < S_TOTAL) unsafeAtomicAdd(&kinA[j], acc0);
        acc0 = acc1; acc1 = 0.f;
        jBase += 64;
        amp1 *= dq1; amp2 *= dq2;
        ran = 1;
        if (jBase >= S_TOTAL) { ran = 0; break; }
    }
    if (ran) {
        int j = jBase + lane;
        if (j < S_TOTAL) unsafeAtomicAdd(&kinA[j], acc0);
    }
}

// ---------------- launch ----------------
extern "C" void kernel_launch(void* const* d_in, const int* in_sizes, int n_in,
                              void* d_out, int out_size, void* d_ws, size_t ws_size,
                              hipStream_t stream) {
    const float* x     = (const float*)d_in[0];
    const float* gamma = (const float*)d_in[1];
    const float* beta  = (const float*)d_in[2];
    const float* W     = (const float*)d_in[3];
    const float* b     = (const float*)d_in[4];
    float* out = (float*)d_out;

    unsigned char* wsb = (unsigned char*)d_ws;
    float* P    = (float*)wsb;                               // 8*SA f32
    unsigned short* Ahi  = (unsigned short*)(wsb + 9437184);
    unsigned short* Alo  = Ahi  + (size_t)S_TOTAL*DDIM;
    unsigned short* WhiT = Alo  + (size_t)S_TOTAL*DDIM;
    unsigned short* WloT = WhiT + (size_t)NPROJ*DDIM;

    hipMemsetAsync(d_out, 0, (size_t)SA * sizeof(float), stream);

    prep_kernel<<<dim3(1024 + 432), dim3(256), 0, stream>>>(x, gamma, beta, W,
                                                            Ahi, Alo, WhiT, WloT);
    gemm_kernel<<<dim3(S_TOTAL/64, NPROJ/96), dim3(256), 0, stream>>>(Ahi, Alo, WhiT, WloT,
                                                                      b, P, out);
    osc_kernel<<<dim3(S_TOTAL/64, AXES/2), dim3(256), 0, stream>>>(P, out);
}

// Round 7
// 66.347 us; speedup vs baseline: 1.6855x; 1.6734x over previous
//
#include <hip/hip_runtime.h>
#include <math.h>

#define S_TOTAL 4096
#define DDIM    512
#define AXES    72
#define NPROJ   864
#define T_PROP  600
#define SA      (S_TOTAL*AXES)
#define LN_EPS  1e-5f
#define AMP_CUT 4e-6f

typedef __attribute__((ext_vector_type(8))) short short8;
typedef __attribute__((ext_vector_type(4))) float f32x4;

__device__ __forceinline__ float softplus_f(float x) {
    return fmaxf(x, 0.f) + log1pf(expf(-fabsf(x)));
}
__device__ __forceinline__ unsigned short bf_hi(float f) {
    return (unsigned short)(__float_as_uint(f) >> 16);
}

// ---------------- 1. fused LN-stats + bf16 split + W^T split ----------------
__global__ __launch_bounds__(256) void prep_kernel(
        const float* __restrict__ x, const float* __restrict__ gamma,
        const float* __restrict__ beta, const float* __restrict__ W,
        unsigned short* __restrict__ Ahi, unsigned short* __restrict__ Alo,
        unsigned short* __restrict__ WhiT, unsigned short* __restrict__ WloT) {
    __shared__ float Wt[32][33];
    int tid = threadIdx.x;
    int b = blockIdx.x;
    if (b < 1024) {
        int lane = tid & 63, w = tid >> 6;
        int row = b*4 + w;
        const float4* xr = reinterpret_cast<const float4*>(x + (size_t)row * DDIM);
        float4 xv[2] = { xr[lane], xr[lane + 64] };
        float sum = 0.f, ssq = 0.f;
#pragma unroll
        for (int c = 0; c < 2; ++c) {
            sum += (xv[c].x + xv[c].y) + (xv[c].z + xv[c].w);
            ssq += xv[c].x*xv[c].x + xv[c].y*xv[c].y + xv[c].z*xv[c].z + xv[c].w*xv[c].w;
        }
#pragma unroll
        for (int off = 1; off < 64; off <<= 1) {
            sum += __shfl_xor(sum, off);
            ssq += __shfl_xor(ssq, off);
        }
        float m = sum * (1.f/DDIM);
        float r = rsqrtf(ssq * (1.f/DDIM) - m*m + LN_EPS);
        const float4* gp = reinterpret_cast<const float4*>(gamma);
        const float4* bp = reinterpret_cast<const float4*>(beta);
#pragma unroll
        for (int c = 0; c < 2; ++c) {
            float4 gv = gp[lane + 64*c], bv = bp[lane + 64*c];
            float xn[4] = {(xv[c].x-m)*r*gv.x+bv.x, (xv[c].y-m)*r*gv.y+bv.y,
                           (xv[c].z-m)*r*gv.z+bv.z, (xv[c].w-m)*r*gv.w+bv.w};
            ushort4 h4, l4;
            unsigned short* hp = &h4.x;
            unsigned short* lp = &l4.x;
#pragma unroll
            for (int j = 0; j < 4; ++j) {
                unsigned short hi = bf_hi(xn[j]);
                float fhi = __uint_as_float((unsigned)hi << 16);
                hp[j] = hi;
                lp[j] = bf_hi(xn[j] - fhi);
            }
            size_t o = (size_t)row*DDIM + 256*c + lane*4;
            *reinterpret_cast<ushort4*>(&Ahi[o]) = h4;
            *reinterpret_cast<ushort4*>(&Alo[o]) = l4;
        }
    } else {
        int wb = b - 1024;
        int bk = wb / 27, bn = wb - bk*27;
        int tx = tid & 31, ty0 = tid >> 5;
#pragma unroll
        for (int rr = 0; rr < 4; ++rr) {
            int ty = ty0 + rr*8;
            Wt[ty][tx] = W[(size_t)(bk*32 + ty)*NPROJ + bn*32 + tx];
        }
        __syncthreads();
#pragma unroll
        for (int rr = 0; rr < 4; ++rr) {
            int ny = ty0 + rr*8;
            int n = bn*32 + ny;
            int k = bk*32 + tx;
            float f = Wt[tx][ny];
            unsigned short hi = bf_hi(f);
            float fhi = __uint_as_float((unsigned)hi << 16);
            WhiT[(size_t)n*DDIM + k] = hi;
            WloT[(size_t)n*DDIM + k] = bf_hi(f - fhi);
        }
    }
}

// ---------------- 2. split-bf16 MFMA GEMM, global_load_lds staging ----------------
// LDS arena per buffer (ushort offsets): Xhi [0,4096) Xlo [4096,8192)
// Whi [8192,14336) Wlo [14336,20480). 40 segments x 1KB; wave wv owns
// segments wv*10..wv*10+9. Dest is linear lane-order (m104); bank conflicts
// broken by XOR swizzle: LDS slot (row, s16) holds logical k-slot s16^(row&7),
// achieved by pre-swizzling the per-lane GLOBAL source (rule #21).
__global__ __launch_bounds__(256) void gemm_kernel(
        const unsigned short* __restrict__ Ahi, const unsigned short* __restrict__ Alo,
        const unsigned short* __restrict__ WhiT, const unsigned short* __restrict__ WloT,
        const float* __restrict__ bias,
        float* __restrict__ P, float* __restrict__ out) {
    __shared__ __align__(16) unsigned short ldsArena[2*20480];   // 80 KB

    int tid  = threadIdx.x;
    int lane = tid & 63;
    int wv   = tid >> 6;
    int wm   = wv & 1;
    int wn   = wv >> 1;
    int sBase = blockIdx.x * 64;
    int nBase = blockIdx.y * 96;
    int l15 = lane & 15;
    int r7  = l15 & 7;

    // per-lane pre-swizzled global sources for this wave's 10 segments
    int rr = lane >> 3;                    // row within 8-row group
    int jj = ((lane & 7) ^ rr) * 8;        // logical k-slot (elements)
    const unsigned short* gp[10];
#pragma unroll
    for (int g = 0; g < 10; ++g) {
        int seg = wv*10 + g;
        const unsigned short* src;
        int row;
        if (seg < 16) {                    // X segments
            int p = seg >> 3, rg = seg & 7;
            row = sBase + rg*8 + rr;
            src = p ? Alo : Ahi;
        } else {                           // W segments
            int s2 = seg - 16;
            int p = (s2 >= 12) ? 1 : 0, rg = s2 - p*12;
            row = nBase + rg*8 + rr;
            src = p ? WloT : WhiT;
        }
        gp[g] = src + (size_t)row*DDIM + jj;
    }

    f32x4 acc[2][3] = {};
    int cur = 0;

#define STAGE(buf, k0) do {                                                   \
        unsigned short* lb = ldsArena + (buf)*20480 + wv*5120;                \
        _Pragma("unroll")                                                     \
        for (int g = 0; g < 10; ++g)                                          \
            __builtin_amdgcn_global_load_lds(                                 \
                (const __attribute__((address_space(1))) void*)(gp[g] + (k0)),\
                (__attribute__((address_space(3))) void*)(lb + g*512),        \
                16, 0, 0);                                                    \
    } while (0)

    STAGE(0, 0);

#pragma unroll 1
    for (int kt = 0; kt < 8; ++kt) {
        __syncthreads();                        // drains stage(kt)
        if (kt < 7) STAGE(cur ^ 1, (kt+1)*64);  // flies under this chunk's compute

        const char* Bc = (const char*)(ldsArena + cur*20480);
#pragma unroll
        for (int kk = 0; kk < 2; ++kk) {
            int kb = kk*64 + ((lane>>4)<<4);    // k-byte within 128-B row
            short8 xh[2], xl[2], wh[3], wl[3];
#pragma unroll
            for (int mi = 0; mi < 2; ++mi) {
                int row = wm*32 + mi*16 + l15;
                int ad = (row*128 + kb) ^ (r7<<4);
                xh[mi] = *reinterpret_cast<const short8*>(Bc + ad);
                xl[mi] = *reinterpret_cast<const short8*>(Bc + 8192 + ad);
            }
#pragma unroll
            for (int nf = 0; nf < 3; ++nf) {
                int row = wn*48 + nf*16 + l15;
                int ad = (row*128 + kb) ^ (r7<<4);
                wh[nf] = *reinterpret_cast<const short8*>(Bc + 16384 + ad);
                wl[nf] = *reinterpret_cast<const short8*>(Bc + 28672 + ad);
            }
#pragma unroll
            for (int mi = 0; mi < 2; ++mi)
#pragma unroll
                for (int nf = 0; nf < 3; ++nf)
                    acc[mi][nf] = __builtin_amdgcn_mfma_f32_16x16x32_bf16(wh[nf], xh[mi], acc[mi][nf], 0, 0, 0);
#pragma unroll
            for (int mi = 0; mi < 2; ++mi)
#pragma unroll
                for (int nf = 0; nf < 3; ++nf)
                    acc[mi][nf] = __builtin_amdgcn_mfma_f32_16x16x32_bf16(wh[nf], xl[mi], acc[mi][nf], 0, 0, 0);
#pragma unroll
            for (int mi = 0; mi < 2; ++mi)
#pragma unroll
                for (int nf = 0; nf < 3; ++nf)
                    acc[mi][nf] = __builtin_amdgcn_mfma_f32_16x16x32_bf16(wl[nf], xh[mi], acc[mi][nf], 0, 0, 0);
        }
        cur ^= 1;
    }
#undef STAGE

    // epilogue: D rows = n, D cols = s (coalesced)
    int sCol = sBase + wm*32 + l15;
    int nRowBase = nBase + wn*48 + ((lane>>4)<<2);
#pragma unroll
    for (int mi = 0; mi < 2; ++mi) {
        int s = sCol + mi*16;
#pragma unroll
        for (int nf = 0; nf < 3; ++nf) {
#pragma unroll
            for (int r = 0; r < 4; ++r) {
                int n = nRowBase + nf*16 + r;
                float val = acc[mi][nf][r] + bias[n];
                int ip = (n * 3641) >> 18;   // n / 72
                int a  = n - ip * 72;
                float res;
                if (ip == 0 || ip == 2)      res = sqrtf(softplus_f(val));
                else if (ip == 1 || ip == 3 || ip == 9 || ip == 11) res = softplus_f(val);
                else                          res = val;
                float* dst = (ip < 8) ? (P + (size_t)ip * SA)
                                      : (out + (size_t)(ip - 7) * SA);
                dst[(size_t)a * S_TOTAL + s] = res;
            }
        }
    }
}

// ---------------- 3. oscillator: order-2 recurrences + rotation scatter ----------------
template<int STEPS>
__device__ __forceinline__ void osc_chunk(
        float& v1a, float& v1b, float& v2a, float& v2b,
        float p1, float q1, float p2, float q2,
        float& acc0, float& acc1, int lane, int lane4) {
#pragma unroll
    for (int i = 0; i < STEPS/2; ++i) {
        {
            const int dt = 2*i;
            v1b = fmaf(p1, v1a, -(q1*v1b));
            v2b = fmaf(p2, v2a, -(q2*v2b));
            float v = v1b + v2b;
            if (dt == 0) {
                acc0 += v;
            } else {
                int addr = (lane4 + (((64-dt)&63)<<2)) & 255;
                float vr = __int_as_float(__builtin_amdgcn_ds_bpermute(addr, __float_as_int(v)));
                bool nw = lane >= dt;
                acc0 += nw ? vr : 0.f;
                acc1 += nw ? 0.f : vr;
            }
        }
        {
            const int dt = 2*i + 1;
            v1a = fmaf(p1, v1b, -(q1*v1a));
            v2a = fmaf(p2, v2b, -(q2*v2a));
            float v = v1a + v2a;
            int addr = (lane4 + (((64-dt)&63)<<2)) & 255;
            float vr = __int_as_float(__builtin_amdgcn_ds_bpermute(addr, __float_as_int(v)));
            bool nw = lane >= dt;
            acc0 += nw ? vr : 0.f;
            acc1 += nw ? 0.f : vr;
        }
    }
}

__global__ __launch_bounds__(256) void osc_kernel(const float* __restrict__ P,
                                                  float* __restrict__ kin) {
    int tid  = threadIdx.x;
    int lane = tid & 63;
    int wv   = tid >> 6;
    int lane4 = lane << 2;
    int sBase = blockIdx.x * 64;
    int a  = blockIdx.y * 2 + (wv >> 1);
    int t0 = (wv & 1) * 300;
    float t0f = (float)t0;

    size_t base = (size_t)a * S_TOTAL + sBase + lane;
    float om1 = P[0*(size_t)SA + base], d1 = P[1*(size_t)SA + base];
    float om2 = P[2*(size_t)SA + base], d2 = P[3*(size_t)SA + base];
    float c1  = P[4*(size_t)SA + base], c2  = P[5*(size_t)SA + base];
    float ph1 = P[6*(size_t)SA + base], ph2 = P[7*(size_t)SA + base];

    float dcf1 = __expf(-0.5f*d1);
    float e1   = c1 * __expf(-0.5f*d1*t0f);
    float s0, c0, so, co;
    __sincosf(fmaf(t0f, om1, ph1), &s0, &c0);
    __sincosf(om1, &so, &co);
    float inv1 = __expf(0.5f*d1);
    float p1 = 2.f*dcf1*co, q1 = dcf1*dcf1;
    float v1a = e1*inv1*(s0*co - c0*so);
    float cs2 = fmaf(2.f*co, co, -1.f), sn2 = 2.f*so*co;
    float v1b = e1*inv1*inv1*(s0*cs2 - c0*sn2);
    float amp1 = fabsf(e1);
    float dq1 = q1*q1; dq1*=dq1; dq1*=dq1; dq1*=dq1; dq1*=dq1;
    float dcf2 = __expf(-0.5f*d2);
    float e2   = c2 * __expf(-0.5f*d2*t0f);
    __sincosf(fmaf(t0f, om2, ph2), &s0, &c0);
    __sincosf(om2, &so, &co);
    float inv2 = __expf(0.5f*d2);
    float p2 = 2.f*dcf2*co, q2 = dcf2*dcf2;
    float v2a = e2*inv2*(s0*co - c0*so);
    cs2 = fmaf(2.f*co, co, -1.f); sn2 = 2.f*so*co;
    float v2b = e2*inv2*inv2*(s0*cs2 - c0*sn2);
    float amp2 = fabsf(e2);
    float dq2 = q2*q2; dq2*=dq2; dq2*=dq2; dq2*=dq2; dq2*=dq2;

    float acc0 = 0.f, acc1 = 0.f;
    float* kinA = kin + (size_t)a * S_TOTAL;
    int jBase = sBase + t0;
    int ran = 0;

#pragma unroll 1
    for (int c = 0; c < 5; ++c) {
        if (__all(fmaxf(amp1, amp2) < AMP_CUT)) break;
        if (c < 4) osc_chunk<64>(v1a, v1b, v2a, v2b, p1, q1, p2, q2, acc0, acc1, lane, lane4);
        else       osc_chunk<44>(v1a, v1b, v2a, v2b, p1, q1, p2, q2, acc0, acc1, lane, lane4);
        int j = jBase + lane;
        if (j < S_TOTAL) unsafeAtomicAdd(&kinA[j], acc0);
        acc0 = acc1; acc1 = 0.f;
        jBase += 64;
        amp1 *= dq1; amp2 *= dq2;
        ran = 1;
        if (jBase >= S_TOTAL) { ran = 0; break; }
    }
    if (ran) {
        int j = jBase + lane;
        if (j < S_TOTAL) unsafeAtomicAdd(&kinA[j], acc0);
    }
}

// ---------------- launch ----------------
extern "C" void kernel_launch(void* const* d_in, const int* in_sizes, int n_in,
                              void* d_out, int out_size, void* d_ws, size_t ws_size,
                              hipStream_t stream) {
    const float* x     = (const float*)d_in[0];
    const float* gamma = (const float*)d_in[1];
    const float* beta  = (const float*)d_in[2];
    const float* W     = (const float*)d_in[3];
    const float* b     = (const float*)d_in[4];
    float* out = (float*)d_out;

    unsigned char* wsb = (unsigned char*)d_ws;
    float* P    = (float*)wsb;                               // 8*SA f32
    unsigned short* Ahi  = (unsigned short*)(wsb + 9437184);
    unsigned short* Alo  = Ahi  + (size_t)S_TOTAL*DDIM;
    unsigned short* WhiT = Alo  + (size_t)S_TOTAL*DDIM;
    unsigned short* WloT = WhiT + (size_t)NPROJ*DDIM;

    hipMemsetAsync(d_out, 0, (size_t)SA * sizeof(float), stream);

    prep_kernel<<<dim3(1024 + 432), dim3(256), 0, stream>>>(x, gamma, beta, W,
                                                            Ahi, Alo, WhiT, WloT);
    gemm_kernel<<<dim3(S_TOTAL/64, NPROJ/96), dim3(256), 0, stream>>>(Ahi, Alo, WhiT, WloT,
                                                                      b, P, out);
    osc_kernel<<<dim3(S_TOTAL/64, AXES/2), dim3(256), 0, stream>>>(P, out);
}

// Round 8
// 61.149 us; speedup vs baseline: 1.8288x; 1.0850x over previous
//
#include <hip/hip_runtime.h>
#include <math.h>

#define S_TOTAL 4096
#define DDIM    512
#define AXES    72
#define NPROJ   864
#define T_PROP  600
#define SA      (S_TOTAL*AXES)
#define LN_EPS  1e-5f
#define AMP_CUT 4e-6f

typedef __attribute__((ext_vector_type(8))) short short8;
typedef __attribute__((ext_vector_type(4))) float f32x4;

__device__ __forceinline__ float softplus_f(float x) {
    return fmaxf(x, 0.f) + log1pf(expf(-fabsf(x)));
}
__device__ __forceinline__ unsigned short bf_hi(float f) {
    return (unsigned short)(__float_as_uint(f) >> 16);
}

// ---------------- 1. fused LN-stats + bf16 split + W^T split + kin zero ----------------
// block ranges: [0,1024) xn rows, [1024,1456) W tiles, [1456,1492) zero kin
__global__ __launch_bounds__(256) void prep_kernel(
        const float* __restrict__ x, const float* __restrict__ gamma,
        const float* __restrict__ beta, const float* __restrict__ W,
        unsigned short* __restrict__ Ahi, unsigned short* __restrict__ Alo,
        unsigned short* __restrict__ WhiT, unsigned short* __restrict__ WloT,
        float* __restrict__ kin) {
    __shared__ float Wt[32][33];
    int tid = threadIdx.x;
    int b = blockIdx.x;
    if (b < 1024) {
        int lane = tid & 63, w = tid >> 6;
        int row = b*4 + w;
        const float4* xr = reinterpret_cast<const float4*>(x + (size_t)row * DDIM);
        float4 xv[2] = { xr[lane], xr[lane + 64] };
        float sum = 0.f, ssq = 0.f;
#pragma unroll
        for (int c = 0; c < 2; ++c) {
            sum += (xv[c].x + xv[c].y) + (xv[c].z + xv[c].w);
            ssq += xv[c].x*xv[c].x + xv[c].y*xv[c].y + xv[c].z*xv[c].z + xv[c].w*xv[c].w;
        }
#pragma unroll
        for (int off = 1; off < 64; off <<= 1) {
            sum += __shfl_xor(sum, off);
            ssq += __shfl_xor(ssq, off);
        }
        float m = sum * (1.f/DDIM);
        float r = rsqrtf(ssq * (1.f/DDIM) - m*m + LN_EPS);
        const float4* gp = reinterpret_cast<const float4*>(gamma);
        const float4* bp = reinterpret_cast<const float4*>(beta);
#pragma unroll
        for (int c = 0; c < 2; ++c) {
            float4 gv = gp[lane + 64*c], bv = bp[lane + 64*c];
            float xn[4] = {(xv[c].x-m)*r*gv.x+bv.x, (xv[c].y-m)*r*gv.y+bv.y,
                           (xv[c].z-m)*r*gv.z+bv.z, (xv[c].w-m)*r*gv.w+bv.w};
            ushort4 h4, l4;
            unsigned short* hp = &h4.x;
            unsigned short* lp = &l4.x;
#pragma unroll
            for (int j = 0; j < 4; ++j) {
                unsigned short hi = bf_hi(xn[j]);
                float fhi = __uint_as_float((unsigned)hi << 16);
                hp[j] = hi;
                lp[j] = bf_hi(xn[j] - fhi);
            }
            size_t o = (size_t)row*DDIM + 256*c + lane*4;
            *reinterpret_cast<ushort4*>(&Ahi[o]) = h4;
            *reinterpret_cast<ushort4*>(&Alo[o]) = l4;
        }
    } else if (b < 1456) {
        int wb = b - 1024;
        int bk = wb / 27, bn = wb - bk*27;
        int tx = tid & 31, ty0 = tid >> 5;
#pragma unroll
        for (int rr = 0; rr < 4; ++rr) {
            int ty = ty0 + rr*8;
            Wt[ty][tx] = W[(size_t)(bk*32 + ty)*NPROJ + bn*32 + tx];
        }
        __syncthreads();
#pragma unroll
        for (int rr = 0; rr < 4; ++rr) {
            int ny = ty0 + rr*8;
            int n = bn*32 + ny;
            int k = bk*32 + tx;
            float f = Wt[tx][ny];
            unsigned short hi = bf_hi(f);
            float fhi = __uint_as_float((unsigned)hi << 16);
            WhiT[(size_t)n*DDIM + k] = hi;
            WloT[(size_t)n*DDIM + k] = bf_hi(f - fhi);
        }
    } else {
        // zero kinematics plane: 36 blocks x 256 threads x 8 float4 = 294912 floats
        int zb = b - 1456;
        float4 z4 = make_float4(0.f, 0.f, 0.f, 0.f);
        float4* kp = reinterpret_cast<float4*>(kin);
#pragma unroll
        for (int i = 0; i < 8; ++i)
            kp[zb*2048 + i*256 + tid] = z4;
    }
}

// ---------------- 2. split-bf16 MFMA GEMM, global_load_lds staging ----------------
// LDS arena per buffer (ushort offsets): Xhi [0,4096) Xlo [4096,8192)
// Whi [8192,14336) Wlo [14336,20480). 40 segments x 1KB; wave wv owns
// segments wv*10..wv*10+9. Dest is linear lane-order (m104); bank conflicts
// broken by XOR swizzle: LDS slot (row, s16) holds logical k-slot s16^(row&7),
// achieved by pre-swizzling the per-lane GLOBAL source (rule #21).
__global__ __launch_bounds__(256) void gemm_kernel(
        const unsigned short* __restrict__ Ahi, const unsigned short* __restrict__ Alo,
        const unsigned short* __restrict__ WhiT, const unsigned short* __restrict__ WloT,
        const float* __restrict__ bias,
        float* __restrict__ P, float* __restrict__ out) {
    __shared__ __align__(16) unsigned short ldsArena[2*20480];   // 80 KB

    int tid  = threadIdx.x;
    int lane = tid & 63;
    int wv   = tid >> 6;
    int wm   = wv & 1;
    int wn   = wv >> 1;
    int sBase = blockIdx.x * 64;
    int nBase = blockIdx.y * 96;
    int l15 = lane & 15;
    int r7  = l15 & 7;

    // per-lane pre-swizzled global sources for this wave's 10 segments
    int rr = lane >> 3;                    // row within 8-row group
    int jj = ((lane & 7) ^ rr) * 8;        // logical k-slot (elements)
    const unsigned short* gp[10];
#pragma unroll
    for (int g = 0; g < 10; ++g) {
        int seg = wv*10 + g;
        const unsigned short* src;
        int row;
        if (seg < 16) {                    // X segments
            int p = seg >> 3, rg = seg & 7;
            row = sBase + rg*8 + rr;
            src = p ? Alo : Ahi;
        } else {                           // W segments
            int s2 = seg - 16;
            int p = (s2 >= 12) ? 1 : 0, rg = s2 - p*12;
            row = nBase + rg*8 + rr;
            src = p ? WloT : WhiT;
        }
        gp[g] = src + (size_t)row*DDIM + jj;
    }

    f32x4 acc[2][3] = {};
    int cur = 0;

#define STAGE(buf, k0) do {                                                   \
        unsigned short* lb = ldsArena + (buf)*20480 + wv*5120;                \
        _Pragma("unroll")                                                     \
        for (int g = 0; g < 10; ++g)                                          \
            __builtin_amdgcn_global_load_lds(                                 \
                (const __attribute__((address_space(1))) void*)(gp[g] + (k0)),\
                (__attribute__((address_space(3))) void*)(lb + g*512),        \
                16, 0, 0);                                                    \
    } while (0)

    STAGE(0, 0);

#pragma unroll 1
    for (int kt = 0; kt < 8; ++kt) {
        __syncthreads();                        // drains stage(kt)
        if (kt < 7) STAGE(cur ^ 1, (kt+1)*64);  // flies under this chunk's compute

        const char* Bc = (const char*)(ldsArena + cur*20480);
#pragma unroll
        for (int kk = 0; kk < 2; ++kk) {
            int kb = kk*64 + ((lane>>4)<<4);    // k-byte within 128-B row
            short8 xh[2], xl[2], wh[3], wl[3];
#pragma unroll
            for (int mi = 0; mi < 2; ++mi) {
                int row = wm*32 + mi*16 + l15;
                int ad = (row*128 + kb) ^ (r7<<4);
                xh[mi] = *reinterpret_cast<const short8*>(Bc + ad);
                xl[mi] = *reinterpret_cast<const short8*>(Bc + 8192 + ad);
            }
#pragma unroll
            for (int nf = 0; nf < 3; ++nf) {
                int row = wn*48 + nf*16 + l15;
                int ad = (row*128 + kb) ^ (r7<<4);
                wh[nf] = *reinterpret_cast<const short8*>(Bc + 16384 + ad);
                wl[nf] = *reinterpret_cast<const short8*>(Bc + 28672 + ad);
            }
#pragma unroll
            for (int mi = 0; mi < 2; ++mi)
#pragma unroll
                for (int nf = 0; nf < 3; ++nf)
                    acc[mi][nf] = __builtin_amdgcn_mfma_f32_16x16x32_bf16(wh[nf], xh[mi], acc[mi][nf], 0, 0, 0);
#pragma unroll
            for (int mi = 0; mi < 2; ++mi)
#pragma unroll
                for (int nf = 0; nf < 3; ++nf)
                    acc[mi][nf] = __builtin_amdgcn_mfma_f32_16x16x32_bf16(wh[nf], xl[mi], acc[mi][nf], 0, 0, 0);
#pragma unroll
            for (int mi = 0; mi < 2; ++mi)
#pragma unroll
                for (int nf = 0; nf < 3; ++nf)
                    acc[mi][nf] = __builtin_amdgcn_mfma_f32_16x16x32_bf16(wl[nf], xh[mi], acc[mi][nf], 0, 0, 0);
        }
        cur ^= 1;
    }
#undef STAGE

    // epilogue: D rows = n, D cols = s (coalesced)
    int sCol = sBase + wm*32 + l15;
    int nRowBase = nBase + wn*48 + ((lane>>4)<<2);
#pragma unroll
    for (int mi = 0; mi < 2; ++mi) {
        int s = sCol + mi*16;
#pragma unroll
        for (int nf = 0; nf < 3; ++nf) {
#pragma unroll
            for (int r = 0; r < 4; ++r) {
                int n = nRowBase + nf*16 + r;
                float val = acc[mi][nf][r] + bias[n];
                int ip = (n * 3641) >> 18;   // n / 72
                int a  = n - ip * 72;
                float res;
                if (ip == 0 || ip == 2)      res = sqrtf(softplus_f(val));
                else if (ip == 1 || ip == 3 || ip == 9 || ip == 11) res = softplus_f(val);
                else                          res = val;
                float* dst = (ip < 8) ? (P + (size_t)ip * SA)
                                      : (out + (size_t)(ip - 7) * SA);
                dst[(size_t)a * S_TOTAL + s] = res;
            }
        }
    }
}

// ---------------- 3. oscillator: order-2 recurrences + rotation scatter ----------------
template<int STEPS>
__device__ __forceinline__ void osc_chunk(
        float& v1a, float& v1b, float& v2a, float& v2b,
        float p1, float q1, float p2, float q2,
        float& acc0, float& acc1, int lane, int lane4) {
#pragma unroll
    for (int i = 0; i < STEPS/2; ++i) {
        {
            const int dt = 2*i;
            v1b = fmaf(p1, v1a, -(q1*v1b));
            v2b = fmaf(p2, v2a, -(q2*v2b));
            float v = v1b + v2b;
            if (dt == 0) {
                acc0 += v;
            } else {
                int addr = (lane4 + (((64-dt)&63)<<2)) & 255;
                float vr = __int_as_float(__builtin_amdgcn_ds_bpermute(addr, __float_as_int(v)));
                bool nw = lane >= dt;
                acc0 += nw ? vr : 0.f;
                acc1 += nw ? 0.f : vr;
            }
        }
        {
            const int dt = 2*i + 1;
            v1a = fmaf(p1, v1b, -(q1*v1a));
            v2a = fmaf(p2, v2b, -(q2*v2a));
            float v = v1a + v2a;
            int addr = (lane4 + (((64-dt)&63)<<2)) & 255;
            float vr = __int_as_float(__builtin_amdgcn_ds_bpermute(addr, __float_as_int(v)));
            bool nw = lane >= dt;
            acc0 += nw ? vr : 0.f;
            acc1 += nw ? 0.f : vr;
        }
    }
}

__global__ __launch_bounds__(256) void osc_kernel(const float* __restrict__ P,
                                                  float* __restrict__ kin) {
    int tid  = threadIdx.x;
    int lane = tid & 63;
    int wv   = tid >> 6;
    int lane4 = lane << 2;
    int sBase = blockIdx.x * 64;
    int a  = blockIdx.y * 2 + (wv >> 1);
    int t0 = (wv & 1) * 300;
    float t0f = (float)t0;

    size_t base = (size_t)a * S_TOTAL + sBase + lane;
    float om1 = P[0*(size_t)SA + base], d1 = P[1*(size_t)SA + base];
    float om2 = P[2*(size_t)SA + base], d2 = P[3*(size_t)SA + base];
    float c1  = P[4*(size_t)SA + base], c2  = P[5*(size_t)SA + base];
    float ph1 = P[6*(size_t)SA + base], ph2 = P[7*(size_t)SA + base];

    float dcf1 = __expf(-0.5f*d1);
    float e1   = c1 * __expf(-0.5f*d1*t0f);
    float s0, c0, so, co;
    __sincosf(fmaf(t0f, om1, ph1), &s0, &c0);
    __sincosf(om1, &so, &co);
    float inv1 = __expf(0.5f*d1);
    float p1 = 2.f*dcf1*co, q1 = dcf1*dcf1;
    float v1a = e1*inv1*(s0*co - c0*so);
    float cs2 = fmaf(2.f*co, co, -1.f), sn2 = 2.f*so*co;
    float v1b = e1*inv1*inv1*(s0*cs2 - c0*sn2);
    float amp1 = fabsf(e1);
    float dq1 = q1*q1; dq1*=dq1; dq1*=dq1; dq1*=dq1; dq1*=dq1;
    float dcf2 = __expf(-0.5f*d2);
    float e2   = c2 * __expf(-0.5f*d2*t0f);
    __sincosf(fmaf(t0f, om2, ph2), &s0, &c0);
    __sincosf(om2, &so, &co);
    float inv2 = __expf(0.5f*d2);
    float p2 = 2.f*dcf2*co, q2 = dcf2*dcf2;
    float v2a = e2*inv2*(s0*co - c0*so);
    cs2 = fmaf(2.f*co, co, -1.f); sn2 = 2.f*so*co;
    float v2b = e2*inv2*inv2*(s0*cs2 - c0*sn2);
    float amp2 = fabsf(e2);
    float dq2 = q2*q2; dq2*=dq2; dq2*=dq2; dq2*=dq2; dq2*=dq2;

    float acc0 = 0.f, acc1 = 0.f;
    float* kinA = kin + (size_t)a * S_TOTAL;
    int jBase = sBase + t0;
    int ran = 0;

#pragma unroll 1
    for (int c = 0; c < 5; ++c) {
        if (__all(fmaxf(amp1, amp2) < AMP_CUT)) break;
        if (c < 4) osc_chunk<64>(v1a, v1b, v2a, v2b, p1, q1, p2, q2, acc0, acc1, lane, lane4);
        else       osc_chunk<44>(v1a, v1b, v2a, v2b, p1, q1, p2, q2, acc0, acc1, lane, lane4);
        int j = jBase + lane;
        if (j < S_TOTAL) unsafeAtomicAdd(&kinA[j], acc0);
        acc0 = acc1; acc1 = 0.f;
        jBase += 64;
        amp1 *= dq1; amp2 *= dq2;
        ran = 1;
        if (jBase >= S_TOTAL) { ran = 0; break; }
    }
    if (ran) {
        int j = jBase + lane;
        if (j < S_TOTAL) unsafeAtomicAdd(&kinA[j], acc0);
    }
}

// ---------------- launch ----------------
extern "C" void kernel_launch(void* const* d_in, const int* in_sizes, int n_in,
                              void* d_out, int out_size, void* d_ws, size_t ws_size,
                              hipStream_t stream) {
    const float* x     = (const float*)d_in[0];
    const float* gamma = (const float*)d_in[1];
    const float* beta  = (const float*)d_in[2];
    const float* W     = (const float*)d_in[3];
    const float* b     = (const float*)d_in[4];
    float* out = (float*)d_out;

    unsigned char* wsb = (unsigned char*)d_ws;
    float* P    = (float*)wsb;                               // 8*SA f32
    unsigned short* Ahi  = (unsigned short*)(wsb + 9437184);
    unsigned short* Alo  = Ahi  + (size_t)S_TOTAL*DDIM;
    unsigned short* WhiT = Alo  + (size_t)S_TOTAL*DDIM;
    unsigned short* WloT = WhiT + (size_t)NPROJ*DDIM;

    prep_kernel<<<dim3(1024 + 432 + 36), dim3(256), 0, stream>>>(x, gamma, beta, W,
                                                                 Ahi, Alo, WhiT, WloT, out);
    gemm_kernel<<<dim3(S_TOTAL/64, NPROJ/96), dim3(256), 0, stream>>>(Ahi, Alo, WhiT, WloT,
                                                                      b, P, out);
    osc_kernel<<<dim3(S_TOTAL/64, AXES/2), dim3(256), 0, stream>>>(P, out);
}